// Round 1
// baseline (2558.113 us; speedup 1.0000x reference)
//
#include <hip/hip_runtime.h>

#define NQ 64
#define ND 50000
#define QTOK 32
#define DTOK 16
#define EMB 768
#define HID 512
#define CHUNK 12500

// ---------------- token mean-pool: [rows, T, EMB] -> [rows, EMB] ----------------
// grid = rows, block = 192 (EMB/4 float4 per row)
__global__ void pool_kernel(const float* __restrict__ in, float* __restrict__ out, int T) {
    int r = blockIdx.x;
    int t = threadIdx.x;  // 0..191
    const float4* ip = (const float4*)in + (size_t)r * T * (EMB / 4);
    float4 acc = make_float4(0.f, 0.f, 0.f, 0.f);
    for (int i = 0; i < T; ++i) {
        float4 v = ip[(size_t)i * (EMB / 4) + t];
        acc.x += v.x; acc.y += v.y; acc.z += v.z; acc.w += v.w;
    }
    float s = 1.0f / (float)T;
    acc.x *= s; acc.y *= s; acc.z *= s; acc.w *= s;
    ((float4*)out)[(size_t)r * (EMB / 4) + t] = acc;
}

// ---------------- fp32 GEMM: C[M,N] = A[M,K] @ W[K,N] + bias (opt ReLU) ----------------
// BM=64, BN=64, BK=16; 256 threads (16x16), 4x4 outputs/thread.
template <int RELU>
__global__ __launch_bounds__(256) void gemm_nn(const float* __restrict__ A,
                                               const float* __restrict__ W,
                                               const float* __restrict__ bias,
                                               float* __restrict__ C,
                                               int M, int K, int N) {
    __shared__ float As[16][68];  // [k][m], padded stride 68 (float4-aligned, <=2-way conflict)
    __shared__ float Bs[16][64];  // [k][n]
    const int bm = blockIdx.x * 64;
    const int bn = blockIdx.y * 64;
    const int tid = threadIdx.x;
    const int tx = tid & 15, ty = tid >> 4;
    float acc[4][4] = {};
    for (int k0 = 0; k0 < K; k0 += 16) {
        {   // A tile: 64 rows x 16 k; one float4 per thread
            int row = tid >> 2;
            int kk  = (tid & 3) << 2;
            int gr  = bm + row;
            float4 v = make_float4(0.f, 0.f, 0.f, 0.f);
            if (gr < M) v = *(const float4*)(A + (size_t)gr * K + k0 + kk);
            As[kk + 0][row] = v.x;
            As[kk + 1][row] = v.y;
            As[kk + 2][row] = v.z;
            As[kk + 3][row] = v.w;
        }
        {   // B tile: 16 k-rows x 64 n; coalesced 64-wide rows
            int n  = tid & 63;
            int kb = tid >> 6;
            #pragma unroll
            for (int q = 0; q < 4; ++q) {
                int kr = kb + q * 4;
                Bs[kr][n] = W[(size_t)(k0 + kr) * N + bn + n];
            }
        }
        __syncthreads();
        #pragma unroll
        for (int k = 0; k < 16; ++k) {
            float4 av = *(const float4*)&As[k][ty << 2];
            float4 bv = *(const float4*)&Bs[k][tx << 2];
            float a[4] = {av.x, av.y, av.z, av.w};
            float b[4] = {bv.x, bv.y, bv.z, bv.w};
            #pragma unroll
            for (int i = 0; i < 4; ++i)
                #pragma unroll
                for (int j = 0; j < 4; ++j)
                    acc[i][j] = fmaf(a[i], b[j], acc[i][j]);
        }
        __syncthreads();
    }
    #pragma unroll
    for (int i = 0; i < 4; ++i) {
        int gr = bm + (ty << 2) + i;
        if (gr >= M) continue;
        #pragma unroll
        for (int j = 0; j < 4; ++j) {
            int gc = bn + (tx << 2) + j;
            float v = acc[i][j] + bias[gc];
            if (RELU) v = fmaxf(v, 0.0f);
            C[(size_t)gr * N + gc] = v;
        }
    }
}

// ---------------- in-place LayerNorm over rows of HID=512 ----------------
// block 256 = 4 waves, one row per wave; each lane owns 8 consecutive floats (in-place safe)
__global__ __launch_bounds__(256) void ln_kernel(float* __restrict__ x,
                                                 const float* __restrict__ g,
                                                 const float* __restrict__ be, int M) {
    int wave = threadIdx.x >> 6, lane = threadIdx.x & 63;
    int row = blockIdx.x * 4 + wave;
    if (row >= M) return;
    float4* p = (float4*)(x + (size_t)row * HID);
    float4 a = p[lane * 2], b = p[lane * 2 + 1];
    float s  = a.x + a.y + a.z + a.w + b.x + b.y + b.z + b.w;
    float sq = a.x*a.x + a.y*a.y + a.z*a.z + a.w*a.w
             + b.x*b.x + b.y*b.y + b.z*b.z + b.w*b.w;
    #pragma unroll
    for (int o = 32; o > 0; o >>= 1) { s += __shfl_xor(s, o); sq += __shfl_xor(sq, o); }
    float mu  = s * (1.0f / HID);
    float var = sq * (1.0f / HID) - mu * mu;
    float r   = rsqrtf(var + 1e-5f);
    const float4* gp = (const float4*)g;
    const float4* bp = (const float4*)be;
    float4 g0 = gp[lane * 2], g1 = gp[lane * 2 + 1];
    float4 b0 = bp[lane * 2], b1 = bp[lane * 2 + 1];
    a.x = (a.x - mu) * r * g0.x + b0.x;  a.y = (a.y - mu) * r * g0.y + b0.y;
    a.z = (a.z - mu) * r * g0.z + b0.z;  a.w = (a.w - mu) * r * g0.w + b0.w;
    b.x = (b.x - mu) * r * g1.x + b1.x;  b.y = (b.y - mu) * r * g1.y + b1.y;
    b.z = (b.z - mu) * r * g1.z + b1.z;  b.w = (b.w - mu) * r * g1.w + b1.w;
    p[lane * 2] = a; p[lane * 2 + 1] = b;
}

// ---------------- in-place L2 normalize rows of HID=512 ----------------
__global__ __launch_bounds__(256) void l2_kernel(float* __restrict__ x, int M) {
    int wave = threadIdx.x >> 6, lane = threadIdx.x & 63;
    int row = blockIdx.x * 4 + wave;
    if (row >= M) return;
    float4* p = (float4*)(x + (size_t)row * HID);
    float4 a = p[lane * 2], b = p[lane * 2 + 1];
    float sq = a.x*a.x + a.y*a.y + a.z*a.z + a.w*a.w
             + b.x*b.x + b.y*b.y + b.z*b.z + b.w*b.w;
    #pragma unroll
    for (int o = 32; o > 0; o >>= 1) sq += __shfl_xor(sq, o);
    float n = sqrtf(sq);
    float r = 1.0f / fmaxf(n, 1e-12f);
    a.x *= r; a.y *= r; a.z *= r; a.w *= r;
    b.x *= r; b.y *= r; b.z *= r; b.w *= r;
    p[lane * 2] = a; p[lane * 2 + 1] = b;
}

// ---------------- scores: S[64, nd] = Q[64,HID] @ D[nd,HID]^T / T ----------------
__global__ __launch_bounds__(256) void gemm_nt(const float* __restrict__ Q,
                                               const float* __restrict__ D,
                                               const float* __restrict__ temp,
                                               float* __restrict__ S,
                                               int nd, int ld) {
    __shared__ float Qs[16][68];
    __shared__ float Ds[16][68];
    const int bn = blockIdx.x * 64;
    const int tid = threadIdx.x;
    const int tx = tid & 15, ty = tid >> 4;
    float acc[4][4] = {};
    for (int k0 = 0; k0 < HID; k0 += 16) {
        int row = tid >> 2;
        int kk  = (tid & 3) << 2;
        float4 v = *(const float4*)(Q + (size_t)row * HID + k0 + kk);
        Qs[kk + 0][row] = v.x; Qs[kk + 1][row] = v.y;
        Qs[kk + 2][row] = v.z; Qs[kk + 3][row] = v.w;
        float4 w = make_float4(0.f, 0.f, 0.f, 0.f);
        int gd = bn + row;
        if (gd < nd) w = *(const float4*)(D + (size_t)gd * HID + k0 + kk);
        Ds[kk + 0][row] = w.x; Ds[kk + 1][row] = w.y;
        Ds[kk + 2][row] = w.z; Ds[kk + 3][row] = w.w;
        __syncthreads();
        #pragma unroll
        for (int k = 0; k < 16; ++k) {
            float4 av = *(const float4*)&Qs[k][ty << 2];
            float4 bv = *(const float4*)&Ds[k][tx << 2];
            float a[4] = {av.x, av.y, av.z, av.w};
            float b[4] = {bv.x, bv.y, bv.z, bv.w};
            #pragma unroll
            for (int i = 0; i < 4; ++i)
                #pragma unroll
                for (int j = 0; j < 4; ++j)
                    acc[i][j] = fmaf(a[i], b[j], acc[i][j]);
        }
        __syncthreads();
    }
    float invT = 1.0f / temp[0];
    #pragma unroll
    for (int i = 0; i < 4; ++i) {
        int gr = (ty << 2) + i;  // query row, always < 64
        #pragma unroll
        for (int j = 0; j < 4; ++j) {
            int gc = bn + (tx << 2) + j;
            if (gc < nd) S[(size_t)gr * ld + gc] = acc[i][j] * invT;
        }
    }
}

// ---------------- top-8 per row with lowest-index tie-break ----------------
__global__ __launch_bounds__(256) void topk_kernel(const float* __restrict__ scores,
                                                   float* __restrict__ out_scores,
                                                   int* __restrict__ out_idx, int N) {
    __shared__ float ls[2048];
    __shared__ int   li[2048];
    const int q   = blockIdx.x;
    const int tid = threadIdx.x;
    const float* row = scores + (size_t)q * N;
    float s[8]; int ix[8];
    #pragma unroll
    for (int i = 0; i < 8; ++i) { s[i] = -1e30f; ix[i] = 0x7fffffff; }
    // per-thread top-8 over strided range (j increases -> strict > keeps lowest idx on ties)
    for (int j = tid; j < N; j += 256) {
        float v = row[j];
        if (v > s[7]) {
            s[7] = v; ix[7] = j;
            #pragma unroll
            for (int t = 7; t > 0; --t) {
                bool sw = (s[t] > s[t-1]) || (s[t] == s[t-1] && ix[t] < ix[t-1]);
                if (sw) {
                    float tv = s[t]; s[t] = s[t-1]; s[t-1] = tv;
                    int   ti = ix[t]; ix[t] = ix[t-1]; ix[t-1] = ti;
                }
            }
        }
    }
    #pragma unroll
    for (int i = 0; i < 8; ++i) { ls[tid * 8 + i] = s[i]; li[tid * 8 + i] = ix[i]; }
    __syncthreads();
    // tree merge: 256 -> 64 -> 16 -> 4 -> 1 lists (merge 4 sorted lists of 8 each step)
    for (int w = 64; w >= 1; w >>= 2) {
        if (tid < w) {
            #pragma unroll
            for (int i = 0; i < 8; ++i) { s[i] = -1e30f; ix[i] = 0x7fffffff; }
            #pragma unroll
            for (int c = 0; c < 32; ++c) {
                float v  = ls[tid * 32 + c];
                int   vi = li[tid * 32 + c];
                bool better = (v > s[7]) || (v == s[7] && vi < ix[7]);
                if (better) {
                    s[7] = v; ix[7] = vi;
                    #pragma unroll
                    for (int t = 7; t > 0; --t) {
                        bool sw = (s[t] > s[t-1]) || (s[t] == s[t-1] && ix[t] < ix[t-1]);
                        if (sw) {
                            float tv = s[t]; s[t] = s[t-1]; s[t-1] = tv;
                            int   ti = ix[t]; ix[t] = ix[t-1]; ix[t-1] = ti;
                        }
                    }
                }
            }
        }
        __syncthreads();
        if (tid < w) {
            #pragma unroll
            for (int i = 0; i < 8; ++i) { ls[tid * 8 + i] = s[i]; li[tid * 8 + i] = ix[i]; }
        }
        __syncthreads();
    }
    if (tid < 8) {
        out_scores[(size_t)q * 8 + tid] = ls[tid];
        out_idx[q * 8 + tid]            = li[tid];
    }
}

// ---------------- gather retrieved docs: out[b] = docs[idx[b]] ----------------
__global__ __launch_bounds__(256) void gather_kernel(const float* __restrict__ docs,
                                                     const int* __restrict__ idx,
                                                     float* __restrict__ out) {
    const int b = blockIdx.x;   // 0..511 (q*8+k)
    const int d = idx[b];
    const float4* src = (const float4*)(docs + (size_t)d * DTOK * EMB);
    float4*       dst = (float4*)(out + (size_t)b * DTOK * EMB);
    for (int i = threadIdx.x; i < DTOK * EMB / 4; i += 256) dst[i] = src[i];
}

extern "C" void kernel_launch(void* const* d_in, const int* in_sizes, int n_in,
                              void* d_out, int out_size, void* d_ws, size_t ws_size,
                              hipStream_t stream) {
    const float* qe   = (const float*)d_in[0];
    const float* de   = (const float*)d_in[1];
    const float* qW1  = (const float*)d_in[2];
    const float* qb1  = (const float*)d_in[3];
    const float* qW2  = (const float*)d_in[4];
    const float* qb2  = (const float*)d_in[5];
    const float* qg   = (const float*)d_in[6];
    const float* qbe  = (const float*)d_in[7];
    const float* dW1  = (const float*)d_in[8];
    const float* db1  = (const float*)d_in[9];
    const float* dW2  = (const float*)d_in[10];
    const float* db2  = (const float*)d_in[11];
    const float* dg   = (const float*)d_in[12];
    const float* dbe  = (const float*)d_in[13];
    const float* pW   = (const float*)d_in[14];
    const float* pb   = (const float*)d_in[15];
    const float* temp = (const float*)d_in[16];

    float* out = (float*)d_out;

    // workspace layout (floats): ~103 MB total
    float* scores = (float*)d_ws;                       // 64*50000
    float* pooled = scores + (size_t)NQ * ND;           // CHUNK*768
    float* h1     = pooled + (size_t)CHUNK * EMB;       // CHUNK*512
    float* h2     = h1 + (size_t)CHUNK * HID;           // CHUNK*512
    float* qpool  = h2 + (size_t)CHUNK * HID;           // 64*768
    float* qh1    = qpool + (size_t)NQ * EMB;           // 64*512
    float* qh2    = qh1 + (size_t)NQ * HID;             // 64*512
    float* qn     = qh2 + (size_t)NQ * HID;             // 64*512
    int*   tidx   = (int*)(qn + (size_t)NQ * HID);      // 64*8

    // ---- query path (tiny) ----
    pool_kernel<<<NQ, 192, 0, stream>>>(qe, qpool, QTOK);
    gemm_nn<1><<<dim3(1, 8), 256, 0, stream>>>(qpool, qW1, qb1, qh1, NQ, EMB, HID);
    gemm_nn<0><<<dim3(1, 8), 256, 0, stream>>>(qh1, qW2, qb2, qh2, NQ, HID, HID);
    ln_kernel<<<(NQ + 3) / 4, 256, 0, stream>>>(qh2, qg, qbe, NQ);
    gemm_nn<0><<<dim3(1, 8), 256, 0, stream>>>(qh2, pW, pb, qn, NQ, HID, HID);
    l2_kernel<<<(NQ + 3) / 4, 256, 0, stream>>>(qn, NQ);

    // ---- doc path in chunks of 12500 ----
    for (int c = 0; c < ND; c += CHUNK) {
        int m = (ND - c < CHUNK) ? (ND - c) : CHUNK;
        pool_kernel<<<m, 192, 0, stream>>>(de + (size_t)c * DTOK * EMB, pooled, DTOK);
        gemm_nn<1><<<dim3((m + 63) / 64, 8), 256, 0, stream>>>(pooled, dW1, db1, h1, m, EMB, HID);
        gemm_nn<0><<<dim3((m + 63) / 64, 8), 256, 0, stream>>>(h1, dW2, db2, h2, m, HID, HID);
        ln_kernel<<<(m + 3) / 4, 256, 0, stream>>>(h2, dg, dbe, m);
        gemm_nn<0><<<dim3((m + 63) / 64, 8), 256, 0, stream>>>(h2, pW, pb, h1, m, HID, HID);
        l2_kernel<<<(m + 3) / 4, 256, 0, stream>>>(h1, m);
        gemm_nt<<<(m + 63) / 64, 256, 0, stream>>>(qn, h1, temp, scores + c, m, ND);
    }

    // ---- top-k + gather ----
    topk_kernel<<<NQ, 256, 0, stream>>>(scores, out, tidx, ND);
    gather_kernel<<<NQ * 8, 256, 0, stream>>>(de, tidx, out + NQ * 8);
}

// Round 2
// 2193.784 us; speedup vs baseline: 1.1661x; 1.1661x over previous
//
#include <hip/hip_runtime.h>

#define NQ 64
#define ND 50000
#define QTOK 32
#define DTOK 16
#define EMB 768
#define HID 512
#define CHUNK 8192

typedef short s16x8 __attribute__((ext_vector_type(8)));
typedef float f32x4 __attribute__((ext_vector_type(4)));

// ---------- bf16 helpers (RNE) ----------
__device__ __forceinline__ unsigned short f2bf(float f) {
    union { float f; unsigned u; } x; x.f = f;
    unsigned r = x.u + 0x7fffu + ((x.u >> 16) & 1u);
    return (unsigned short)(r >> 16);
}
__device__ __forceinline__ float bf2f(unsigned short h) {
    union { unsigned u; float f; } x; x.u = ((unsigned)h) << 16;
    return x.f;
}
// Two values -> 3 packed uints of the activation-augmented stream (hi,lo,hi | hi,lo,hi)
__device__ __forceinline__ void pack2(float va, float vb, unsigned& w0, unsigned& w1, unsigned& w2) {
    unsigned ha = f2bf(va); unsigned la = f2bf(va - bf2f((unsigned short)ha));
    unsigned hb = f2bf(vb); unsigned lb = f2bf(vb - bf2f((unsigned short)hb));
    w0 = ha | (la << 16);
    w1 = ha | (hb << 16);
    w2 = lb | (hb << 16);
}

__device__ __forceinline__ void gload_lds16(const void* g, void* l) {
    __builtin_amdgcn_global_load_lds(
        (const __attribute__((address_space(1))) void*)g,
        (__attribute__((address_space(3))) void*)l, 16, 0, 0);
}

// ---------------- fp32 mean-pool (query path): [rows,T,EMB] -> [rows,EMB] ----------------
__global__ void pool_kernel(const float* __restrict__ in, float* __restrict__ out, int T) {
    int r = blockIdx.x;
    int t = threadIdx.x;  // 0..191
    const float4* ip = (const float4*)in + (size_t)r * T * (EMB / 4);
    float4 acc = make_float4(0.f, 0.f, 0.f, 0.f);
    for (int i = 0; i < T; ++i) {
        float4 v = ip[(size_t)i * (EMB / 4) + t];
        acc.x += v.x; acc.y += v.y; acc.z += v.z; acc.w += v.w;
    }
    float s = 1.0f / (float)T;
    acc.x *= s; acc.y *= s; acc.z *= s; acc.w *= s;
    ((float4*)out)[(size_t)r * (EMB / 4) + t] = acc;
}

// ---------------- doc mean-pool -> augmented bf16 [rows][3*EMB] ----------------
__global__ void pool_aug(const float* __restrict__ in, ushort* __restrict__ out) {
    int r = blockIdx.x, t = threadIdx.x;  // 192 threads, 4 floats each
    const float4* ip = (const float4*)in + (size_t)r * DTOK * (EMB / 4) + t;
    float4 a = make_float4(0.f, 0.f, 0.f, 0.f);
    #pragma unroll
    for (int i = 0; i < DTOK; ++i) {
        float4 v = ip[(size_t)i * (EMB / 4)];
        a.x += v.x; a.y += v.y; a.z += v.z; a.w += v.w;
    }
    const float s = 1.0f / (float)DTOK;
    unsigned w0, w1, w2, w3, w4, w5;
    pack2(a.x * s, a.y * s, w0, w1, w2);
    pack2(a.z * s, a.w * s, w3, w4, w5);
    uint2* q = (uint2*)(out + (size_t)r * (3 * EMB) + t * 12);  // byte off = r*4608 + t*24 (8B aligned)
    q[0] = make_uint2(w0, w1); q[1] = make_uint2(w2, w3); q[2] = make_uint2(w4, w5);
}

// ---------------- weight convert: W[K][512] fp32 -> Wp[512][3K] bf16 (hi,hi,lo) ----------------
__global__ void wconv(const float* __restrict__ W, ushort* __restrict__ Wp, int K) {
    int n = blockIdx.x;  // 512 blocks
    for (int k = threadIdx.x; k < K; k += blockDim.x) {
        float v = W[(size_t)k * HID + n];
        unsigned short hi = f2bf(v);
        unsigned short lo = f2bf(v - bf2f(hi));
        ushort* p = Wp + (size_t)n * 3 * K + 3 * k;
        p[0] = hi; p[1] = hi; p[2] = lo;
    }
}

// ---------------- MFMA GEMM: C[M,512] = A'[M,K2] x Wp[512,K2]^T (+bias, epilogue) ----------------
// A' augmented bf16 (hi,lo,hi), Wp augmented bf16 (hi,hi,lo). Tile 128x64, BK=64, 256 thr = 4 waves.
// MODE 0: write fp32 C[M][512].  MODE 1: relu, write augmented bf16 out[M][3*512].
template <int MODE>
__global__ __launch_bounds__(256) void mfma_gemm(const ushort* __restrict__ A,
                                                 const ushort* __restrict__ B,
                                                 const float* __restrict__ bias,
                                                 void* __restrict__ out,
                                                 int M, int K2) {
    __shared__ ushort As[128 * 64];  // [row][k] 16KB
    __shared__ ushort Bs[64 * 64];   // [n][k]   8KB
    const int bm = blockIdx.x * 128;
    const int bn = blockIdx.y * 64;
    const int tid = threadIdx.x;
    const int lane = tid & 63, wave = tid >> 6;
    f32x4 acc[2][4] = {};

    for (int k0 = 0; k0 < K2; k0 += 64) {
        // stage A: 4 calls x (256 thr x 16B) = 16KB, linear LDS
        #pragma unroll
        for (int c = 0; c < 4; ++c) {
            int row = c * 32 + (tid >> 3);
            int grow = bm + row; if (grow > M - 1) grow = M - 1;
            const ushort* gp = A + (size_t)grow * K2 + k0 + ((tid & 7) << 3);
            gload_lds16(gp, As + row * 64 + ((tid & 7) << 3));
        }
        // stage B: 2 calls = 8KB
        #pragma unroll
        for (int c = 0; c < 2; ++c) {
            int n = c * 32 + (tid >> 3);
            const ushort* gp = B + (size_t)(bn + n) * K2 + k0 + ((tid & 7) << 3);
            gload_lds16(gp, Bs + n * 64 + ((tid & 7) << 3));
        }
        __syncthreads();  // compiler drains vmcnt before s_barrier

        #pragma unroll
        for (int kk = 0; kk < 2; ++kk) {
            const int ko = kk * 32 + ((lane >> 4) << 3);  // element offset in k
            s16x8 a[2], b[4];
            #pragma unroll
            for (int i = 0; i < 2; ++i) {
                int r = wave * 32 + i * 16 + (lane & 15);
                a[i] = *(const s16x8*)(As + r * 64 + ko);
            }
            #pragma unroll
            for (int j = 0; j < 4; ++j) {
                int n = j * 16 + (lane & 15);
                b[j] = *(const s16x8*)(Bs + n * 64 + ko);
            }
            #pragma unroll
            for (int i = 0; i < 2; ++i)
                #pragma unroll
                for (int j = 0; j < 4; ++j)
                    acc[i][j] = __builtin_amdgcn_mfma_f32_16x16x32_bf16(a[i], b[j], acc[i][j], 0, 0, 0);
        }
        __syncthreads();
    }

    // epilogue: C/D layout col=lane&15, row=(lane>>4)*4+reg
    #pragma unroll
    for (int j = 0; j < 4; ++j) {
        int col = bn + j * 16 + (lane & 15);
        float bv = bias[col];
        #pragma unroll
        for (int i = 0; i < 2; ++i) {
            #pragma unroll
            for (int r = 0; r < 4; ++r) {
                int grow = bm + wave * 32 + i * 16 + ((lane >> 4) << 2) + r;
                if (grow >= M) continue;
                float v = acc[i][j][r] + bv;
                if (MODE == 1) {
                    v = fmaxf(v, 0.0f);
                    unsigned short hi = f2bf(v);
                    unsigned short lo = f2bf(v - bf2f(hi));
                    ushort* op = (ushort*)out + (size_t)grow * (3 * HID) + 3 * col;
                    op[0] = hi; op[1] = lo; op[2] = hi;
                } else {
                    ((float*)out)[(size_t)grow * HID + col] = v;
                }
            }
        }
    }
}

// ---------------- in-place fp32 LayerNorm (query path) ----------------
__global__ __launch_bounds__(256) void ln_kernel(float* __restrict__ x,
                                                 const float* __restrict__ g,
                                                 const float* __restrict__ be, int M) {
    int wv = threadIdx.x >> 6, lane = threadIdx.x & 63;
    int row = blockIdx.x * 4 + wv;
    if (row >= M) return;
    float4* p = (float4*)(x + (size_t)row * HID);
    float4 a = p[lane * 2], b = p[lane * 2 + 1];
    float s  = a.x + a.y + a.z + a.w + b.x + b.y + b.z + b.w;
    float sq = a.x*a.x + a.y*a.y + a.z*a.z + a.w*a.w
             + b.x*b.x + b.y*b.y + b.z*b.z + b.w*b.w;
    #pragma unroll
    for (int o = 32; o > 0; o >>= 1) { s += __shfl_xor(s, o); sq += __shfl_xor(sq, o); }
    float mu  = s * (1.0f / HID);
    float var = sq * (1.0f / HID) - mu * mu;
    float r   = rsqrtf(var + 1e-5f);
    const float4* gp = (const float4*)g;
    const float4* bp = (const float4*)be;
    float4 g0 = gp[lane * 2], g1 = gp[lane * 2 + 1];
    float4 b0 = bp[lane * 2], b1 = bp[lane * 2 + 1];
    a.x = (a.x - mu) * r * g0.x + b0.x;  a.y = (a.y - mu) * r * g0.y + b0.y;
    a.z = (a.z - mu) * r * g0.z + b0.z;  a.w = (a.w - mu) * r * g0.w + b0.w;
    b.x = (b.x - mu) * r * g1.x + b1.x;  b.y = (b.y - mu) * r * g1.y + b1.y;
    b.z = (b.z - mu) * r * g1.z + b1.z;  b.w = (b.w - mu) * r * g1.w + b1.w;
    p[lane * 2] = a; p[lane * 2 + 1] = b;
}

// ---------------- LayerNorm fp32 -> augmented bf16 [M][3*HID] (doc path) ----------------
__global__ __launch_bounds__(256) void ln_aug(const float* __restrict__ x,
                                              const float* __restrict__ g,
                                              const float* __restrict__ be,
                                              ushort* __restrict__ out, int M) {
    int wv = threadIdx.x >> 6, lane = threadIdx.x & 63;
    int row = blockIdx.x * 4 + wv;
    if (row >= M) return;
    const float4* p = (const float4*)(x + (size_t)row * HID);
    float4 a = p[lane * 2], b = p[lane * 2 + 1];
    float s  = a.x + a.y + a.z + a.w + b.x + b.y + b.z + b.w;
    float sq = a.x*a.x + a.y*a.y + a.z*a.z + a.w*a.w
             + b.x*b.x + b.y*b.y + b.z*b.z + b.w*b.w;
    #pragma unroll
    for (int o = 32; o > 0; o >>= 1) { s += __shfl_xor(s, o); sq += __shfl_xor(sq, o); }
    float mu  = s * (1.0f / HID);
    float var = sq * (1.0f / HID) - mu * mu;
    float r   = rsqrtf(var + 1e-5f);
    const float4* gp = (const float4*)g;
    const float4* bp = (const float4*)be;
    float4 g0 = gp[lane * 2], g1 = gp[lane * 2 + 1];
    float4 b0 = bp[lane * 2], b1 = bp[lane * 2 + 1];
    float v0 = (a.x - mu) * r * g0.x + b0.x, v1 = (a.y - mu) * r * g0.y + b0.y;
    float v2 = (a.z - mu) * r * g0.z + b0.z, v3 = (a.w - mu) * r * g0.w + b0.w;
    float v4 = (b.x - mu) * r * g1.x + b1.x, v5 = (b.y - mu) * r * g1.y + b1.y;
    float v6 = (b.z - mu) * r * g1.z + b1.z, v7 = (b.w - mu) * r * g1.w + b1.w;
    unsigned w[12];
    pack2(v0, v1, w[0], w[1], w[2]);
    pack2(v2, v3, w[3], w[4], w[5]);
    pack2(v4, v5, w[6], w[7], w[8]);
    pack2(v6, v7, w[9], w[10], w[11]);
    uint4* q = (uint4*)(out + (size_t)row * (3 * HID) + lane * 24);  // byte off = row*3072 + lane*48 (16B)
    q[0] = make_uint4(w[0], w[1], w[2], w[3]);
    q[1] = make_uint4(w[4], w[5], w[6], w[7]);
    q[2] = make_uint4(w[8], w[9], w[10], w[11]);
}

// ---------------- in-place L2 normalize rows of HID ----------------
__global__ __launch_bounds__(256) void l2_kernel(float* __restrict__ x, int M) {
    int wv = threadIdx.x >> 6, lane = threadIdx.x & 63;
    int row = blockIdx.x * 4 + wv;
    if (row >= M) return;
    float4* p = (float4*)(x + (size_t)row * HID);
    float4 a = p[lane * 2], b = p[lane * 2 + 1];
    float sq = a.x*a.x + a.y*a.y + a.z*a.z + a.w*a.w
             + b.x*b.x + b.y*b.y + b.z*b.z + b.w*b.w;
    #pragma unroll
    for (int o = 32; o > 0; o >>= 1) sq += __shfl_xor(sq, o);
    float n = sqrtf(sq);
    float r = 1.0f / fmaxf(n, 1e-12f);
    a.x *= r; a.y *= r; a.z *= r; a.w *= r;
    b.x *= r; b.y *= r; b.z *= r; b.w *= r;
    p[lane * 2] = a; p[lane * 2 + 1] = b;
}

// ---------------- fp32 GEMM for the tiny query path ----------------
template <int RELU>
__global__ __launch_bounds__(256) void gemm_nn(const float* __restrict__ A,
                                               const float* __restrict__ W,
                                               const float* __restrict__ bias,
                                               float* __restrict__ C,
                                               int M, int K, int N) {
    __shared__ float As[16][68];
    __shared__ float Bs[16][64];
    const int bm = blockIdx.x * 64;
    const int bn = blockIdx.y * 64;
    const int tid = threadIdx.x;
    const int tx = tid & 15, ty = tid >> 4;
    float acc[4][4] = {};
    for (int k0 = 0; k0 < K; k0 += 16) {
        {
            int row = tid >> 2;
            int kk  = (tid & 3) << 2;
            int gr  = bm + row;
            float4 v = make_float4(0.f, 0.f, 0.f, 0.f);
            if (gr < M) v = *(const float4*)(A + (size_t)gr * K + k0 + kk);
            As[kk + 0][row] = v.x; As[kk + 1][row] = v.y;
            As[kk + 2][row] = v.z; As[kk + 3][row] = v.w;
        }
        {
            int n  = tid & 63;
            int kb = tid >> 6;
            #pragma unroll
            for (int q = 0; q < 4; ++q) {
                int kr = kb + q * 4;
                Bs[kr][n] = W[(size_t)(k0 + kr) * N + bn + n];
            }
        }
        __syncthreads();
        #pragma unroll
        for (int k = 0; k < 16; ++k) {
            float4 av = *(const float4*)&As[k][ty << 2];
            float4 bv = *(const float4*)&Bs[k][tx << 2];
            float a[4] = {av.x, av.y, av.z, av.w};
            float b[4] = {bv.x, bv.y, bv.z, bv.w};
            #pragma unroll
            for (int i = 0; i < 4; ++i)
                #pragma unroll
                for (int j = 0; j < 4; ++j)
                    acc[i][j] = fmaf(a[i], b[j], acc[i][j]);
        }
        __syncthreads();
    }
    #pragma unroll
    for (int i = 0; i < 4; ++i) {
        int gr = bm + (ty << 2) + i;
        if (gr >= M) continue;
        #pragma unroll
        for (int j = 0; j < 4; ++j) {
            int gc = bn + (tx << 2) + j;
            float v = acc[i][j] + bias[gc];
            if (RELU) v = fmaxf(v, 0.0f);
            C[(size_t)gr * N + gc] = v;
        }
    }
}

// ---------------- scores: S[64, nd] = Q[64,HID] @ D[nd,HID]^T / T ----------------
__global__ __launch_bounds__(256) void gemm_nt(const float* __restrict__ Q,
                                               const float* __restrict__ D,
                                               const float* __restrict__ temp,
                                               float* __restrict__ S,
                                               int nd, int ld) {
    __shared__ float Qs[16][68];
    __shared__ float Ds[16][68];
    const int bn = blockIdx.x * 64;
    const int tid = threadIdx.x;
    const int tx = tid & 15, ty = tid >> 4;
    float acc[4][4] = {};
    for (int k0 = 0; k0 < HID; k0 += 16) {
        int row = tid >> 2;
        int kk  = (tid & 3) << 2;
        float4 v = *(const float4*)(Q + (size_t)row * HID + k0 + kk);
        Qs[kk + 0][row] = v.x; Qs[kk + 1][row] = v.y;
        Qs[kk + 2][row] = v.z; Qs[kk + 3][row] = v.w;
        float4 w = make_float4(0.f, 0.f, 0.f, 0.f);
        int gd = bn + row;
        if (gd < nd) w = *(const float4*)(D + (size_t)gd * HID + k0 + kk);
        Ds[kk + 0][row] = w.x; Ds[kk + 1][row] = w.y;
        Ds[kk + 2][row] = w.z; Ds[kk + 3][row] = w.w;
        __syncthreads();
        #pragma unroll
        for (int k = 0; k < 16; ++k) {
            float4 av = *(const float4*)&Qs[k][ty << 2];
            float4 bv = *(const float4*)&Ds[k][tx << 2];
            float a[4] = {av.x, av.y, av.z, av.w};
            float b[4] = {bv.x, bv.y, bv.z, bv.w};
            #pragma unroll
            for (int i = 0; i < 4; ++i)
                #pragma unroll
                for (int j = 0; j < 4; ++j)
                    acc[i][j] = fmaf(a[i], b[j], acc[i][j]);
        }
        __syncthreads();
    }
    float invT = 1.0f / temp[0];
    #pragma unroll
    for (int i = 0; i < 4; ++i) {
        int gr = (ty << 2) + i;
        #pragma unroll
        for (int j = 0; j < 4; ++j) {
            int gc = bn + (tx << 2) + j;
            if (gc < nd) S[(size_t)gr * ld + gc] = acc[i][j] * invT;
        }
    }
}

// ---------------- top-8 per row with lowest-index tie-break ----------------
__global__ __launch_bounds__(256) void topk_kernel(const float* __restrict__ scores,
                                                   float* __restrict__ out_scores,
                                                   int* __restrict__ out_idx, int N) {
    __shared__ float ls[2048];
    __shared__ int   li[2048];
    const int q   = blockIdx.x;
    const int tid = threadIdx.x;
    const float* row = scores + (size_t)q * N;
    float s[8]; int ix[8];
    #pragma unroll
    for (int i = 0; i < 8; ++i) { s[i] = -1e30f; ix[i] = 0x7fffffff; }
    for (int j = tid; j < N; j += 256) {
        float v = row[j];
        if (v > s[7]) {
            s[7] = v; ix[7] = j;
            #pragma unroll
            for (int t = 7; t > 0; --t) {
                bool sw = (s[t] > s[t-1]) || (s[t] == s[t-1] && ix[t] < ix[t-1]);
                if (sw) {
                    float tv = s[t]; s[t] = s[t-1]; s[t-1] = tv;
                    int   ti = ix[t]; ix[t] = ix[t-1]; ix[t-1] = ti;
                }
            }
        }
    }
    #pragma unroll
    for (int i = 0; i < 8; ++i) { ls[tid * 8 + i] = s[i]; li[tid * 8 + i] = ix[i]; }
    __syncthreads();
    for (int w = 64; w >= 1; w >>= 2) {
        if (tid < w) {
            #pragma unroll
            for (int i = 0; i < 8; ++i) { s[i] = -1e30f; ix[i] = 0x7fffffff; }
            #pragma unroll
            for (int c = 0; c < 32; ++c) {
                float v  = ls[tid * 32 + c];
                int   vi = li[tid * 32 + c];
                bool better = (v > s[7]) || (v == s[7] && vi < ix[7]);
                if (better) {
                    s[7] = v; ix[7] = vi;
                    #pragma unroll
                    for (int t = 7; t > 0; --t) {
                        bool sw = (s[t] > s[t-1]) || (s[t] == s[t-1] && ix[t] < ix[t-1]);
                        if (sw) {
                            float tv = s[t]; s[t] = s[t-1]; s[t-1] = tv;
                            int   ti = ix[t]; ix[t] = ix[t-1]; ix[t-1] = ti;
                        }
                    }
                }
            }
        }
        __syncthreads();
        if (tid < w) {
            #pragma unroll
            for (int i = 0; i < 8; ++i) { ls[tid * 8 + i] = s[i]; li[tid * 8 + i] = ix[i]; }
        }
        __syncthreads();
    }
    if (tid < 8) {
        out_scores[(size_t)q * 8 + tid] = ls[tid];
        out_idx[q * 8 + tid]            = li[tid];
    }
}

// ---------------- gather retrieved docs ----------------
__global__ __launch_bounds__(256) void gather_kernel(const float* __restrict__ docs,
                                                     const int* __restrict__ idx,
                                                     float* __restrict__ out) {
    const int b = blockIdx.x;
    const int d = idx[b];
    const float4* src = (const float4*)(docs + (size_t)d * DTOK * EMB);
    float4*       dst = (float4*)(out + (size_t)b * DTOK * EMB);
    for (int i = threadIdx.x; i < DTOK * EMB / 4; i += 256) dst[i] = src[i];
}

extern "C" void kernel_launch(void* const* d_in, const int* in_sizes, int n_in,
                              void* d_out, int out_size, void* d_ws, size_t ws_size,
                              hipStream_t stream) {
    const float* qe   = (const float*)d_in[0];
    const float* de   = (const float*)d_in[1];
    const float* qW1  = (const float*)d_in[2];
    const float* qb1  = (const float*)d_in[3];
    const float* qW2  = (const float*)d_in[4];
    const float* qb2  = (const float*)d_in[5];
    const float* qg   = (const float*)d_in[6];
    const float* qbe  = (const float*)d_in[7];
    const float* dW1  = (const float*)d_in[8];
    const float* db1  = (const float*)d_in[9];
    const float* dW2  = (const float*)d_in[10];
    const float* db2  = (const float*)d_in[11];
    const float* dg   = (const float*)d_in[12];
    const float* dbe  = (const float*)d_in[13];
    const float* pW   = (const float*)d_in[14];
    const float* pb   = (const float*)d_in[15];
    const float* temp = (const float*)d_in[16];

    float* out = (float*)d_out;

    // ---- workspace layout (bytes, all 256B-aligned) ≈ 98.7 MB ----
    char* w = (char*)d_ws;
    float*  scores = (float*)w;                 w += (size_t)NQ * ND * 4;           // 12.8 MB
    ushort* W1p    = (ushort*)w;                w += (size_t)HID * 3 * EMB * 2;     // 2.36 MB
    ushort* W2p    = (ushort*)w;                w += (size_t)HID * 3 * HID * 2;     // 1.57 MB
    ushort* pWp    = (ushort*)w;                w += (size_t)HID * 3 * HID * 2;     // 1.57 MB
    float*  qpool  = (float*)w;                 w += (size_t)NQ * EMB * 4;
    float*  qh1    = (float*)w;                 w += (size_t)NQ * HID * 4;
    float*  qh2    = (float*)w;                 w += (size_t)NQ * HID * 4;
    float*  qn     = (float*)w;                 w += (size_t)NQ * HID * 4;
    int*    tidx   = (int*)w;                   w += (size_t)NQ * 8 * 4;
    ushort* pooled = (ushort*)w;                w += (size_t)CHUNK * 3 * EMB * 2;   // 37.7 MB (aliased by ln')
    ushort* h1a    = (ushort*)w;                w += (size_t)CHUNK * 3 * HID * 2;   // 25.2 MB
    float*  h2     = (float*)w;                 w += (size_t)CHUNK * HID * 4;       // 16.8 MB (aliased by p)
    ushort* lna    = pooled;   // LN output overwrites pooled (dead after GEMM1)
    float*  pproj  = h2;       // GEMM3 output overwrites h2 (dead after LN)

    // ---- weight conversion (tiny) ----
    wconv<<<HID, 256, 0, stream>>>(dW1, W1p, EMB);
    wconv<<<HID, 256, 0, stream>>>(dW2, W2p, HID);
    wconv<<<HID, 256, 0, stream>>>(pW,  pWp, HID);

    // ---- query path (fp32, tiny) ----
    pool_kernel<<<NQ, 192, 0, stream>>>(qe, qpool, QTOK);
    gemm_nn<1><<<dim3(1, 8), 256, 0, stream>>>(qpool, qW1, qb1, qh1, NQ, EMB, HID);
    gemm_nn<0><<<dim3(1, 8), 256, 0, stream>>>(qh1, qW2, qb2, qh2, NQ, HID, HID);
    ln_kernel<<<(NQ + 3) / 4, 256, 0, stream>>>(qh2, qg, qbe, NQ);
    gemm_nn<0><<<dim3(1, 8), 256, 0, stream>>>(qh2, pW, pb, qn, NQ, HID, HID);
    l2_kernel<<<(NQ + 3) / 4, 256, 0, stream>>>(qn, NQ);

    // ---- doc path: chunks of 8192 ----
    for (int c = 0; c < ND; c += CHUNK) {
        int m = (ND - c < CHUNK) ? (ND - c) : CHUNK;
        int gm = (m + 127) / 128;
        pool_aug<<<m, 192, 0, stream>>>(de + (size_t)c * DTOK * EMB, pooled);
        mfma_gemm<1><<<dim3(gm, 8), 256, 0, stream>>>(pooled, W1p, db1, h1a, m, 3 * EMB);
        mfma_gemm<0><<<dim3(gm, 8), 256, 0, stream>>>(h1a, W2p, db2, h2, m, 3 * HID);
        ln_aug<<<(m + 3) / 4, 256, 0, stream>>>(h2, dg, dbe, lna, m);
        mfma_gemm<0><<<dim3(gm, 8), 256, 0, stream>>>(lna, pWp, pb, pproj, m, 3 * HID);
        l2_kernel<<<(m + 3) / 4, 256, 0, stream>>>(pproj, m);
        gemm_nt<<<(m + 63) / 64, 256, 0, stream>>>(qn, pproj, temp, scores + c, m, ND);
    }

    // ---- top-k + gather ----
    topk_kernel<<<NQ, 256, 0, stream>>>(scores, out, tidx, ND);
    gather_kernel<<<NQ * 8, 256, 0, stream>>>(de, tidx, out + NQ * 8);
}

// Round 3
// 1562.833 us; speedup vs baseline: 1.6368x; 1.4037x over previous
//
#include <hip/hip_runtime.h>

#define NQ 64
#define ND 50000
#define QTOK 32
#define DTOK 16
#define EMB 768
#define HID 512

typedef short s16x8 __attribute__((ext_vector_type(8)));
typedef float f32x4 __attribute__((ext_vector_type(4)));

// ---------- bf16 helpers (RNE) ----------
__device__ __forceinline__ unsigned short f2bf(float f) {
    union { float f; unsigned u; } x; x.f = f;
    unsigned r = x.u + 0x7fffu + ((x.u >> 16) & 1u);
    return (unsigned short)(r >> 16);
}
__device__ __forceinline__ float bf2f(unsigned short h) {
    union { unsigned u; float f; } x; x.u = ((unsigned)h) << 16;
    return x.f;
}
// activation stream (hi,lo,hi): pair (va,vb) -> 3 uints
__device__ __forceinline__ void pack2A(float va, float vb, unsigned& w0, unsigned& w1, unsigned& w2) {
    unsigned ha = f2bf(va); unsigned la = f2bf(va - bf2f((unsigned short)ha));
    unsigned hb = f2bf(vb); unsigned lb = f2bf(vb - bf2f((unsigned short)hb));
    w0 = ha | (la << 16);
    w1 = ha | (hb << 16);
    w2 = lb | (hb << 16);
}
// weight stream (hi,hi,lo): pair (va,vb) -> 3 uints
__device__ __forceinline__ void pack2B(float va, float vb, unsigned& w0, unsigned& w1, unsigned& w2) {
    unsigned ha = f2bf(va); unsigned la = f2bf(va - bf2f((unsigned short)ha));
    unsigned hb = f2bf(vb); unsigned lb = f2bf(vb - bf2f((unsigned short)hb));
    w0 = ha | (ha << 16);
    w1 = la | (hb << 16);
    w2 = hb | (lb << 16);
}

__device__ __forceinline__ void gload_lds16(const void* g, void* l) {
    __builtin_amdgcn_global_load_lds(
        (const __attribute__((address_space(1))) void*)g,
        (__attribute__((address_space(3))) void*)l, 16, 0, 0);
}

// ---------------- fp32 mean-pool (query path) ----------------
__global__ void pool_kernel(const float* __restrict__ in, float* __restrict__ out, int T) {
    int r = blockIdx.x;
    int t = threadIdx.x;  // 0..191
    const float4* ip = (const float4*)in + (size_t)r * T * (EMB / 4);
    float4 acc = make_float4(0.f, 0.f, 0.f, 0.f);
    for (int i = 0; i < T; ++i) {
        float4 v = ip[(size_t)i * (EMB / 4) + t];
        acc.x += v.x; acc.y += v.y; acc.z += v.z; acc.w += v.w;
    }
    float s = 1.0f / (float)T;
    acc.x *= s; acc.y *= s; acc.z *= s; acc.w *= s;
    ((float4*)out)[(size_t)r * (EMB / 4) + t] = acc;
}

// ---------------- doc mean-pool -> augmented bf16 [rows][3*EMB] ----------------
__global__ void pool_aug(const float* __restrict__ in, ushort* __restrict__ out) {
    int r = blockIdx.x, t = threadIdx.x;  // 192 threads x 4 floats
    const float4* ip = (const float4*)in + (size_t)r * DTOK * (EMB / 4) + t;
    float4 a = make_float4(0.f, 0.f, 0.f, 0.f);
    #pragma unroll
    for (int i = 0; i < DTOK; ++i) {
        float4 v = ip[(size_t)i * (EMB / 4)];
        a.x += v.x; a.y += v.y; a.z += v.z; a.w += v.w;
    }
    const float s = 1.0f / (float)DTOK;
    unsigned w0, w1, w2, w3, w4, w5;
    pack2A(a.x * s, a.y * s, w0, w1, w2);
    pack2A(a.z * s, a.w * s, w3, w4, w5);
    uint2* q = (uint2*)(out + (size_t)r * (3 * EMB) + t * 12);
    q[0] = make_uint2(w0, w1); q[1] = make_uint2(w2, w3); q[2] = make_uint2(w4, w5);
}

// ---------------- weight convert: W[K][512] fp32 -> Wp[512][3K] bf16 (hi,hi,lo) ----------------
__global__ void wconv(const float* __restrict__ W, ushort* __restrict__ Wp, int K) {
    int n = blockIdx.x;  // 512 blocks
    for (int k = threadIdx.x; k < K; k += blockDim.x) {
        float v = W[(size_t)k * HID + n];
        unsigned short hi = f2bf(v);
        unsigned short lo = f2bf(v - bf2f(hi));
        ushort* p = Wp + (size_t)n * 3 * K + 3 * k;
        p[0] = hi; p[1] = hi; p[2] = lo;
    }
}

// ---------------- MFMA GEMM, tile 128x256, 8 waves, XOR-swizzled LDS ----------------
// A' [M][K2] (hi,lo,hi);  B' [N_B][K2] (hi,hi,lo).
// MODE 0: fp32 out[M][HID] = acc + bias
// MODE 1: relu(acc+bias) -> augmented bf16 out[M][3*HID]
// MODE 2: scores: out[M][ldo] (fp32) = acc * (1/temp[0]), col guard N_B
template <int MODE>
__global__ __launch_bounds__(512) void mfma_gemm2(const ushort* __restrict__ A,
                                                  const ushort* __restrict__ B,
                                                  const float* __restrict__ bias,
                                                  void* __restrict__ out,
                                                  int M, int N_B, int K2, long ldo,
                                                  const float* __restrict__ temp) {
    __shared__ ushort As[128 * 64];  // 16KB, row stride 128B, 16B-slot XOR swizzle
    __shared__ ushort Bs[256 * 64];  // 32KB
    const int bm = blockIdx.x * 128;
    const int bn = blockIdx.y * 256;
    const int tid = threadIdx.x;
    const int lane = tid & 63;
    const int wave = tid >> 6;       // 0..7
    const int wr = wave >> 2;        // 0..1  (row 64-panel)
    const int wc = wave & 3;         // 0..3  (col 64-panel)
    f32x4 acc[4][4] = {};

    for (int k0 = 0; k0 < K2; k0 += 64) {
        // stage A: 2 rounds x 512 lanes x 16B = 16KB; linear LDS dest, swizzled global k-slot
        #pragma unroll
        for (int c = 0; c < 2; ++c) {
            int row = c * 64 + (tid >> 3);
            int s   = tid & 7;
            int grow = bm + row; if (grow >= M) grow = M - 1;
            int ks = (s ^ (row & 7)) << 3;
            gload_lds16(A + (size_t)grow * K2 + k0 + ks, As + row * 64 + s * 8);
        }
        // stage B: 4 rounds = 32KB
        #pragma unroll
        for (int c = 0; c < 4; ++c) {
            int n = c * 64 + (tid >> 3);
            int s = tid & 7;
            int gn = bn + n; if (gn >= N_B) gn = N_B - 1;
            int ks = (s ^ (n & 7)) << 3;
            gload_lds16(B + (size_t)gn * K2 + k0 + ks, Bs + n * 64 + s * 8);
        }
        __syncthreads();

        #pragma unroll
        for (int kk = 0; kk < 2; ++kk) {
            const int sp = kk * 4 + (lane >> 4);  // logical 16B k-slot
            s16x8 a[4], b[4];
            #pragma unroll
            for (int i = 0; i < 4; ++i) {
                int r = wr * 64 + i * 16 + (lane & 15);
                a[i] = *(const s16x8*)(As + r * 64 + ((sp ^ (r & 7)) << 3));
            }
            #pragma unroll
            for (int j = 0; j < 4; ++j) {
                int n = wc * 64 + j * 16 + (lane & 15);
                b[j] = *(const s16x8*)(Bs + n * 64 + ((sp ^ (n & 7)) << 3));
            }
            #pragma unroll
            for (int i = 0; i < 4; ++i)
                #pragma unroll
                for (int j = 0; j < 4; ++j)
                    acc[i][j] = __builtin_amdgcn_mfma_f32_16x16x32_bf16(a[i], b[j], acc[i][j], 0, 0, 0);
        }
        __syncthreads();
    }

    // epilogue: C/D layout col=lane&15, row=(lane>>4)*4+reg
    float scale = (MODE == 2) ? (1.0f / temp[0]) : 0.0f;
    #pragma unroll
    for (int j = 0; j < 4; ++j) {
        int col = bn + wc * 64 + j * 16 + (lane & 15);
        float bv = (MODE == 2) ? 0.0f : bias[col];
        #pragma unroll
        for (int i = 0; i < 4; ++i) {
            #pragma unroll
            for (int r = 0; r < 4; ++r) {
                int grow = bm + wr * 64 + i * 16 + ((lane >> 4) << 2) + r;
                if (grow >= M) continue;
                float v = acc[i][j][r];
                if (MODE == 0) {
                    ((float*)out)[(size_t)grow * HID + col] = v + bv;
                } else if (MODE == 1) {
                    v = fmaxf(v + bv, 0.0f);
                    unsigned short hi = f2bf(v);
                    unsigned short lo = f2bf(v - bf2f(hi));
                    ushort* op = (ushort*)out + (size_t)grow * (3 * HID) + 3 * col;
                    op[0] = hi; op[1] = lo; op[2] = hi;
                } else {
                    if (col < N_B) ((float*)out)[(size_t)grow * ldo + col] = v * scale;
                }
            }
        }
    }
}

// ---------------- in-place fp32 LayerNorm (query path) ----------------
__global__ __launch_bounds__(256) void ln_kernel(float* __restrict__ x,
                                                 const float* __restrict__ g,
                                                 const float* __restrict__ be, int M) {
    int wv = threadIdx.x >> 6, lane = threadIdx.x & 63;
    int row = blockIdx.x * 4 + wv;
    if (row >= M) return;
    float4* p = (float4*)(x + (size_t)row * HID);
    float4 a = p[lane * 2], b = p[lane * 2 + 1];
    float s  = a.x + a.y + a.z + a.w + b.x + b.y + b.z + b.w;
    float sq = a.x*a.x + a.y*a.y + a.z*a.z + a.w*a.w
             + b.x*b.x + b.y*b.y + b.z*b.z + b.w*b.w;
    #pragma unroll
    for (int o = 32; o > 0; o >>= 1) { s += __shfl_xor(s, o); sq += __shfl_xor(sq, o); }
    float mu  = s * (1.0f / HID);
    float var = sq * (1.0f / HID) - mu * mu;
    float r   = rsqrtf(var + 1e-5f);
    const float4* gp = (const float4*)g;
    const float4* bp = (const float4*)be;
    float4 g0 = gp[lane * 2], g1 = gp[lane * 2 + 1];
    float4 b0 = bp[lane * 2], b1 = bp[lane * 2 + 1];
    a.x = (a.x - mu) * r * g0.x + b0.x;  a.y = (a.y - mu) * r * g0.y + b0.y;
    a.z = (a.z - mu) * r * g0.z + b0.z;  a.w = (a.w - mu) * r * g0.w + b0.w;
    b.x = (b.x - mu) * r * g1.x + b1.x;  b.y = (b.y - mu) * r * g1.y + b1.y;
    b.z = (b.z - mu) * r * g1.z + b1.z;  b.w = (b.w - mu) * r * g1.w + b1.w;
    p[lane * 2] = a; p[lane * 2 + 1] = b;
}

// ---------------- LayerNorm fp32 -> augmented A-side bf16 [M][3*HID] ----------------
__global__ __launch_bounds__(256) void ln_aug(const float* __restrict__ x,
                                              const float* __restrict__ g,
                                              const float* __restrict__ be,
                                              ushort* __restrict__ out, int M) {
    int wv = threadIdx.x >> 6, lane = threadIdx.x & 63;
    int row = blockIdx.x * 4 + wv;
    if (row >= M) return;
    const float4* p = (const float4*)(x + (size_t)row * HID);
    float4 a = p[lane * 2], b = p[lane * 2 + 1];
    float s  = a.x + a.y + a.z + a.w + b.x + b.y + b.z + b.w;
    float sq = a.x*a.x + a.y*a.y + a.z*a.z + a.w*a.w
             + b.x*b.x + b.y*b.y + b.z*b.z + b.w*b.w;
    #pragma unroll
    for (int o = 32; o > 0; o >>= 1) { s += __shfl_xor(s, o); sq += __shfl_xor(sq, o); }
    float mu  = s * (1.0f / HID);
    float var = sq * (1.0f / HID) - mu * mu;
    float r   = rsqrtf(var + 1e-5f);
    const float4* gp = (const float4*)g;
    const float4* bp = (const float4*)be;
    float4 g0 = gp[lane * 2], g1 = gp[lane * 2 + 1];
    float4 b0 = bp[lane * 2], b1 = bp[lane * 2 + 1];
    float v0 = (a.x - mu) * r * g0.x + b0.x, v1 = (a.y - mu) * r * g0.y + b0.y;
    float v2 = (a.z - mu) * r * g0.z + b0.z, v3 = (a.w - mu) * r * g0.w + b0.w;
    float v4 = (b.x - mu) * r * g1.x + b1.x, v5 = (b.y - mu) * r * g1.y + b1.y;
    float v6 = (b.z - mu) * r * g1.z + b1.z, v7 = (b.w - mu) * r * g1.w + b1.w;
    unsigned w[12];
    pack2A(v0, v1, w[0], w[1], w[2]);
    pack2A(v2, v3, w[3], w[4], w[5]);
    pack2A(v4, v5, w[6], w[7], w[8]);
    pack2A(v6, v7, w[9], w[10], w[11]);
    uint4* q = (uint4*)(out + (size_t)row * (3 * HID) + lane * 24);
    q[0] = make_uint4(w[0], w[1], w[2], w[3]);
    q[1] = make_uint4(w[4], w[5], w[6], w[7]);
    q[2] = make_uint4(w[8], w[9], w[10], w[11]);
}

// ---------------- L2-normalize fp32 rows -> augmented B-side bf16 [M][3*HID] ----------------
__global__ __launch_bounds__(256) void l2_augB(const float* __restrict__ x,
                                               ushort* __restrict__ out, int M) {
    int wv = threadIdx.x >> 6, lane = threadIdx.x & 63;
    int row = blockIdx.x * 4 + wv;
    if (row >= M) return;
    const float4* p = (const float4*)(x + (size_t)row * HID);
    float4 a = p[lane * 2], b = p[lane * 2 + 1];
    float sq = a.x*a.x + a.y*a.y + a.z*a.z + a.w*a.w
             + b.x*b.x + b.y*b.y + b.z*b.z + b.w*b.w;
    #pragma unroll
    for (int o = 32; o > 0; o >>= 1) sq += __shfl_xor(sq, o);
    float n = sqrtf(sq);
    float r = 1.0f / fmaxf(n, 1e-12f);
    float v0 = a.x*r, v1 = a.y*r, v2 = a.z*r, v3 = a.w*r;
    float v4 = b.x*r, v5 = b.y*r, v6 = b.z*r, v7 = b.w*r;
    unsigned w[12];
    pack2B(v0, v1, w[0], w[1], w[2]);
    pack2B(v2, v3, w[3], w[4], w[5]);
    pack2B(v4, v5, w[6], w[7], w[8]);
    pack2B(v6, v7, w[9], w[10], w[11]);
    uint4* q = (uint4*)(out + (size_t)row * (3 * HID) + lane * 24);
    q[0] = make_uint4(w[0], w[1], w[2], w[3]);
    q[1] = make_uint4(w[4], w[5], w[6], w[7]);
    q[2] = make_uint4(w[8], w[9], w[10], w[11]);
}

// ---------------- in-place L2 normalize (query path fp32) ----------------
__global__ __launch_bounds__(256) void l2_kernel(float* __restrict__ x, int M) {
    int wv = threadIdx.x >> 6, lane = threadIdx.x & 63;
    int row = blockIdx.x * 4 + wv;
    if (row >= M) return;
    float4* p = (float4*)(x + (size_t)row * HID);
    float4 a = p[lane * 2], b = p[lane * 2 + 1];
    float sq = a.x*a.x + a.y*a.y + a.z*a.z + a.w*a.w
             + b.x*b.x + b.y*b.y + b.z*b.z + b.w*b.w;
    #pragma unroll
    for (int o = 32; o > 0; o >>= 1) sq += __shfl_xor(sq, o);
    float n = sqrtf(sq);
    float r = 1.0f / fmaxf(n, 1e-12f);
    a.x *= r; a.y *= r; a.z *= r; a.w *= r;
    b.x *= r; b.y *= r; b.z *= r; b.w *= r;
    p[lane * 2] = a; p[lane * 2 + 1] = b;
}

// ---------------- fp32 -> augmented A-side (queries) ----------------
__global__ __launch_bounds__(256) void fp32_augA(const float* __restrict__ x,
                                                 ushort* __restrict__ out, int M) {
    int wv = threadIdx.x >> 6, lane = threadIdx.x & 63;
    int row = blockIdx.x * 4 + wv;
    if (row >= M) return;
    const float4* p = (const float4*)(x + (size_t)row * HID);
    float4 a = p[lane * 2], b = p[lane * 2 + 1];
    unsigned w[12];
    pack2A(a.x, a.y, w[0], w[1], w[2]);
    pack2A(a.z, a.w, w[3], w[4], w[5]);
    pack2A(b.x, b.y, w[6], w[7], w[8]);
    pack2A(b.z, b.w, w[9], w[10], w[11]);
    uint4* q = (uint4*)(out + (size_t)row * (3 * HID) + lane * 24);
    q[0] = make_uint4(w[0], w[1], w[2], w[3]);
    q[1] = make_uint4(w[4], w[5], w[6], w[7]);
    q[2] = make_uint4(w[8], w[9], w[10], w[11]);
}

// ---------------- fp32 GEMM for the tiny query path ----------------
template <int RELU>
__global__ __launch_bounds__(256) void gemm_nn(const float* __restrict__ A,
                                               const float* __restrict__ W,
                                               const float* __restrict__ bias,
                                               float* __restrict__ C,
                                               int M, int K, int N) {
    __shared__ float As[16][68];
    __shared__ float Bs[16][64];
    const int bm = blockIdx.x * 64;
    const int bn = blockIdx.y * 64;
    const int tid = threadIdx.x;
    const int tx = tid & 15, ty = tid >> 4;
    float acc[4][4] = {};
    for (int k0 = 0; k0 < K; k0 += 16) {
        {
            int row = tid >> 2;
            int kk  = (tid & 3) << 2;
            int gr  = bm + row;
            float4 v = make_float4(0.f, 0.f, 0.f, 0.f);
            if (gr < M) v = *(const float4*)(A + (size_t)gr * K + k0 + kk);
            As[kk + 0][row] = v.x; As[kk + 1][row] = v.y;
            As[kk + 2][row] = v.z; As[kk + 3][row] = v.w;
        }
        {
            int n  = tid & 63;
            int kb = tid >> 6;
            #pragma unroll
            for (int q = 0; q < 4; ++q) {
                int kr = kb + q * 4;
                Bs[kr][n] = W[(size_t)(k0 + kr) * N + bn + n];
            }
        }
        __syncthreads();
        #pragma unroll
        for (int k = 0; k < 16; ++k) {
            float4 av = *(const float4*)&As[k][ty << 2];
            float4 bv = *(const float4*)&Bs[k][tx << 2];
            float a[4] = {av.x, av.y, av.z, av.w};
            float b[4] = {bv.x, bv.y, bv.z, bv.w};
            #pragma unroll
            for (int i = 0; i < 4; ++i)
                #pragma unroll
                for (int j = 0; j < 4; ++j)
                    acc[i][j] = fmaf(a[i], b[j], acc[i][j]);
        }
        __syncthreads();
    }
    #pragma unroll
    for (int i = 0; i < 4; ++i) {
        int gr = bm + (ty << 2) + i;
        if (gr >= M) continue;
        #pragma unroll
        for (int j = 0; j < 4; ++j) {
            int gc = bn + (tx << 2) + j;
            float v = acc[i][j] + bias[gc];
            if (RELU) v = fmaxf(v, 0.0f);
            C[(size_t)gr * N + gc] = v;
        }
    }
}

// ---------------- top-8 per row with lowest-index tie-break ----------------
__global__ __launch_bounds__(256) void topk_kernel(const float* __restrict__ scores,
                                                   float* __restrict__ out_scores,
                                                   int* __restrict__ out_idx, int N) {
    __shared__ float ls[2048];
    __shared__ int   li[2048];
    const int q   = blockIdx.x;
    const int tid = threadIdx.x;
    const float* row = scores + (size_t)q * N;
    float s[8]; int ix[8];
    #pragma unroll
    for (int i = 0; i < 8; ++i) { s[i] = -1e30f; ix[i] = 0x7fffffff; }
    for (int j = tid; j < N; j += 256) {
        float v = row[j];
        if (v > s[7]) {
            s[7] = v; ix[7] = j;
            #pragma unroll
            for (int t = 7; t > 0; --t) {
                bool sw = (s[t] > s[t-1]) || (s[t] == s[t-1] && ix[t] < ix[t-1]);
                if (sw) {
                    float tv = s[t]; s[t] = s[t-1]; s[t-1] = tv;
                    int   ti = ix[t]; ix[t] = ix[t-1]; ix[t-1] = ti;
                }
            }
        }
    }
    #pragma unroll
    for (int i = 0; i < 8; ++i) { ls[tid * 8 + i] = s[i]; li[tid * 8 + i] = ix[i]; }
    __syncthreads();
    for (int w = 64; w >= 1; w >>= 2) {
        if (tid < w) {
            #pragma unroll
            for (int i = 0; i < 8; ++i) { s[i] = -1e30f; ix[i] = 0x7fffffff; }
            #pragma unroll
            for (int c = 0; c < 32; ++c) {
                float v  = ls[tid * 32 + c];
                int   vi = li[tid * 32 + c];
                bool better = (v > s[7]) || (v == s[7] && vi < ix[7]);
                if (better) {
                    s[7] = v; ix[7] = vi;
                    #pragma unroll
                    for (int t = 7; t > 0; --t) {
                        bool sw = (s[t] > s[t-1]) || (s[t] == s[t-1] && ix[t] < ix[t-1]);
                        if (sw) {
                            float tv = s[t]; s[t] = s[t-1]; s[t-1] = tv;
                            int   ti = ix[t]; ix[t] = ix[t-1]; ix[t-1] = ti;
                        }
                    }
                }
            }
        }
        __syncthreads();
        if (tid < w) {
            #pragma unroll
            for (int i = 0; i < 8; ++i) { ls[tid * 8 + i] = s[i]; li[tid * 8 + i] = ix[i]; }
        }
        __syncthreads();
    }
    if (tid < 8) {
        out_scores[(size_t)q * 8 + tid] = ls[tid];
        out_idx[q * 8 + tid]            = li[tid];
    }
}

// ---------------- gather retrieved docs ----------------
__global__ __launch_bounds__(256) void gather_kernel(const float* __restrict__ docs,
                                                     const int* __restrict__ idx,
                                                     float* __restrict__ out) {
    const int b = blockIdx.x;
    const int d = idx[b];
    const float4* src = (const float4*)(docs + (size_t)d * DTOK * EMB);
    float4*       dst = (float4*)(out + (size_t)b * DTOK * EMB);
    for (int i = threadIdx.x; i < DTOK * EMB / 4; i += 256) dst[i] = src[i];
}

extern "C" void kernel_launch(void* const* d_in, const int* in_sizes, int n_in,
                              void* d_out, int out_size, void* d_ws, size_t ws_size,
                              hipStream_t stream) {
    const float* qe   = (const float*)d_in[0];
    const float* de   = (const float*)d_in[1];
    const float* qW1  = (const float*)d_in[2];
    const float* qb1  = (const float*)d_in[3];
    const float* qW2  = (const float*)d_in[4];
    const float* qb2  = (const float*)d_in[5];
    const float* qg   = (const float*)d_in[6];
    const float* qbe  = (const float*)d_in[7];
    const float* dW1  = (const float*)d_in[8];
    const float* db1  = (const float*)d_in[9];
    const float* dW2  = (const float*)d_in[10];
    const float* db2  = (const float*)d_in[11];
    const float* dg   = (const float*)d_in[12];
    const float* dbe  = (const float*)d_in[13];
    const float* pW   = (const float*)d_in[14];
    const float* pb   = (const float*)d_in[15];
    const float* temp = (const float*)d_in[16];

    float* out = (float*)d_out;

    // ---- workspace carve (~510 MB; ws is multi-GB) ----
    char* w = (char*)d_ws;
    float*  scores = (float*)w;                 w += (size_t)NQ * ND * 4;            // 12.8 MB
    ushort* W1p    = (ushort*)w;                w += (size_t)HID * 3 * EMB * 2;      // 2.36 MB
    ushort* W2p    = (ushort*)w;                w += (size_t)HID * 3 * HID * 2;      // 1.57 MB
    ushort* pWp    = (ushort*)w;                w += (size_t)HID * 3 * HID * 2;      // 1.57 MB
    float*  qpool  = (float*)w;                 w += (size_t)NQ * EMB * 4;
    float*  qh1    = (float*)w;                 w += (size_t)NQ * HID * 4;
    float*  qh2    = (float*)w;                 w += (size_t)NQ * HID * 4;
    float*  qn     = (float*)w;                 w += (size_t)NQ * HID * 4;
    ushort* qaug   = (ushort*)w;                w += (size_t)NQ * 3 * HID * 2;       // 196 KB
    int*    tidx   = (int*)w;                   w += 4096;
    ushort* pooled = (ushort*)w;                w += (size_t)ND * 3 * EMB * 2;       // 230.4 MB
    ushort* h1a    = (ushort*)w;                w += (size_t)ND * 3 * HID * 2;       // 153.6 MB
    float*  h2     = (float*)w;                 w += (size_t)ND * HID * 4;           // 102.4 MB
    ushort* lna    = pooled;   // LN-aug overwrites pooled (dead after GEMM1)
    float*  pproj  = h2;       // GEMM3 out overwrites h2 (dead after ln_aug)
    ushort* Daug   = h1a;      // l2_augB overwrites h1a (dead after GEMM2)

    const int GM = (ND + 127) / 128;   // 391

    // ---- weight conversion (tiny) ----
    wconv<<<HID, 256, 0, stream>>>(dW1, W1p, EMB);
    wconv<<<HID, 256, 0, stream>>>(dW2, W2p, HID);
    wconv<<<HID, 256, 0, stream>>>(pW,  pWp, HID);

    // ---- query path (fp32, tiny) ----
    pool_kernel<<<NQ, 192, 0, stream>>>(qe, qpool, QTOK);
    gemm_nn<1><<<dim3(1, 8), 256, 0, stream>>>(qpool, qW1, qb1, qh1, NQ, EMB, HID);
    gemm_nn<0><<<dim3(1, 8), 256, 0, stream>>>(qh1, qW2, qb2, qh2, NQ, HID, HID);
    ln_kernel<<<(NQ + 3) / 4, 256, 0, stream>>>(qh2, qg, qbe, NQ);
    gemm_nn<0><<<dim3(1, 8), 256, 0, stream>>>(qh2, pW, pb, qn, NQ, HID, HID);
    l2_kernel<<<(NQ + 3) / 4, 256, 0, stream>>>(qn, NQ);
    fp32_augA<<<(NQ + 3) / 4, 256, 0, stream>>>(qn, qaug, NQ);

    // ---- doc path, full-M single pass ----
    pool_aug<<<ND, 192, 0, stream>>>(de, pooled);
    mfma_gemm2<1><<<dim3(GM, 2), 512, 0, stream>>>(pooled, W1p, db1, h1a, ND, HID, 3 * EMB, 0, nullptr);
    mfma_gemm2<0><<<dim3(GM, 2), 512, 0, stream>>>(h1a, W2p, db2, h2, ND, HID, 3 * HID, 0, nullptr);
    ln_aug<<<(ND + 3) / 4, 256, 0, stream>>>(h2, dg, dbe, lna, ND);
    mfma_gemm2<0><<<dim3(GM, 2), 512, 0, stream>>>(lna, pWp, pb, pproj, ND, HID, 3 * HID, 0, nullptr);
    l2_augB<<<(ND + 3) / 4, 256, 0, stream>>>(pproj, Daug, ND);

    // ---- scores: [64, ND] = qaug x Daug^T * (1/T) ----
    mfma_gemm2<2><<<dim3(1, (ND + 255) / 256), 512, 0, stream>>>(qaug, Daug, nullptr, scores,
                                                                 NQ, ND, 3 * HID, (long)ND, temp);

    // ---- top-k + gather ----
    topk_kernel<<<NQ, 256, 0, stream>>>(scores, out, tidx, ND);
    gather_kernel<<<NQ * 8, 256, 0, stream>>>(de, tidx, out + NQ * 8);
}